// Round 5
// baseline (10459.210 us; speedup 1.0000x reference)
//
#include <hip/hip_runtime.h>

#define N_PTS 32768
#define HID   100
#define STEPS 100

// Output layout (concatenated flat, fp32):
#define OFF_Z     0
#define OFF_MUXZ  65536
#define OFF_LSXZ  163840
#define OFF_MUZX  262144
#define OFF_LTZX  327680
#define OFF_MUZ   360448
#define OFF_LTZ   425984

typedef float v2f __attribute__((ext_vector_type(2)));

#if __has_builtin(__builtin_elementwise_fma)
#define FMA2(a, b, c) __builtin_elementwise_fma((a), (b), (c))
#else
#define FMA2(a, b, c) ((a) * (b) + (c))
#endif

__device__ __forceinline__ v2f splat(float x) { v2f r; r.x = x; r.y = x; return r; }

// Butterfly sum across a quad of lanes via DPP quad_perm (xor1=0xB1, xor2=0x4E).
__device__ __forceinline__ float qreduce(float v) {
  v += __int_as_float(__builtin_amdgcn_update_dpp(0, __float_as_int(v), 0xB1, 0xF, 0xF, true));
  v += __int_as_float(__builtin_amdgcn_update_dpp(0, __float_as_int(v), 0x4E, 0xF, 0xF, true));
  return v;
}

// ---------------- Encoder: x -> h1 -> h2 -> (mu_zx, log_t_zx) ----------------
__global__ __launch_bounds__(128, 1) void enc_kernel(
    const float* __restrict__ x,
    const float* __restrict__ We1, const float* __restrict__ be1,
    const float* __restrict__ We2, const float* __restrict__ be2,
    const float* __restrict__ Wmu, const float* __restrict__ bmu,
    const float* __restrict__ Wlt, const float* __restrict__ blt,
    const float* __restrict__ b_muz, const float* __restrict__ b_ltz,
    float* __restrict__ out)
{
  const int tid = threadIdx.x;
  const int w   = tid >> 6;           // wave 0/1
  const int pb  = tid & 63;           // point within block
  const int p   = blockIdx.x * 64 + pb;
  const int ob  = __builtin_amdgcn_readfirstlane(w * 50);

  const float x0 = x[p*3+0], x1 = x[p*3+1], x2 = x[p*3+2];

  v2f acc2[25];
  #pragma unroll
  for (int i = 0; i < 25; ++i) { acc2[i].x = 0.f; acc2[i].y = 0.f; }

  for (int k = 0; k < HID; ++k) {
    float a   = fmaf(x0, We1[k], fmaf(x1, We1[HID+k], fmaf(x2, We1[2*HID+k], be1[k])));
    float sig = 1.f / (1.f + __expf(-a));
    float h1  = a * sig;
    const v2f hh = splat(h1);
    const v2f* row2 = (const v2f*)(We2 + k*HID + ob);
    #pragma unroll
    for (int oo = 0; oo < 25; ++oo) acc2[oo] = FMA2(hh, row2[oo], acc2[oo]);
  }

  float m0 = 0.f, m1 = 0.f, lt = 0.f;
  #pragma unroll
  for (int oo = 0; oo < 25; ++oo) {
    #pragma unroll
    for (int h = 0; h < 2; ++h) {
      const int o = ob + 2*oo + h;
      float a   = (h ? acc2[oo].y : acc2[oo].x) + be2[o];
      float sig = 1.f / (1.f + __expf(-a));
      float h2  = a * sig;
      m0 = fmaf(h2, Wmu[o*2+0], m0);
      m1 = fmaf(h2, Wmu[o*2+1], m1);
      lt = fmaf(h2, Wlt[o],     lt);
    }
  }

  __shared__ float red[2][64][3];
  red[w][pb][0] = m0; red[w][pb][1] = m1; red[w][pb][2] = lt;
  __syncthreads();
  if (w == 0) {
    m0 += red[1][pb][0] + bmu[0];
    m1 += red[1][pb][1] + bmu[1];
    lt += red[1][pb][2] + blt[0];
    out[OFF_MUZX + p*2+0] = m0;
    out[OFF_MUZX + p*2+1] = m1;
    out[OFF_LTZX + p]     = lt;
    out[OFF_MUZ  + p*2+0] = b_muz[0];
    out[OFF_MUZ  + p*2+1] = b_muz[1];
    out[OFF_LTZ  + p]     = b_ltz[0];
  }
}

// ------------- SDE: 100 Euler-Maruyama steps on the pullback metric ----------
// Block = 256 threads = 64 points, 4 lanes/point, 25 j/lane.
// Hybrid storage sized to dodge the round-4 scratch-spill cliff (<256 VGPR):
//   registers: {W0,W1,b} per j  -> 75 VGPR/lane (top of the dependency chain)
//   LDS:       {m0,m1,m2,s0,s1,s2,pad,pad} per j, 32 B stride.
//     lane l reads j=l*25+jj: bank base = (l*25+jj)*8 %32 = {0,8,16,24}+...
//     -> the 4 lanes of a quad hit disjoint bank groups; 16 quads broadcast.
// j-loop fully unrolled: immediate LDS offsets, no address math, max ILP.
__global__ __launch_bounds__(256, 2) void sde_kernel(
    const float* __restrict__ Wd1,  const float* __restrict__ bd1,
    const float* __restrict__ Wdmu, const float* __restrict__ bdmu,
    const float* __restrict__ Wds,  const float* __restrict__ bds,
    const float* __restrict__ noise,
    float* __restrict__ out)
{
  __shared__ __align__(16) float hrec[HID*8];
  const int tid = threadIdx.x;
  for (int idx = tid; idx < HID*8; idx += 256) {
    const int j = idx >> 3, f = idx & 7;
    float v = 0.f;
    if      (f < 3) v = Wdmu[j*3 + f];
    else if (f < 6) v = Wds [j*3 + (f-3)];
    hrec[idx] = v;
  }
  __syncthreads();

  const int l     = tid & 3;                    // lane within quad
  const int p     = blockIdx.x * 64 + (tid >> 2);
  const int jbase = l * 25;

  // ---- per-lane register weights (one-time global loads, L2-broadcast) ----
  float W0r[25], W1r[25], brr[25];
  #pragma unroll
  for (int jj = 0; jj < 25; ++jj) {
    const int j = jbase + jj;
    W0r[jj] = Wd1[j];
    W1r[jj] = Wd1[HID + j];
    brr[jj] = bd1[j];
  }

  float z0 = out[OFF_MUZX + p*2+0];
  float z1 = out[OFF_MUZX + p*2+1];
  const float sdt = __expf(out[OFF_LTZX + p]) * 0.1f;  // sqrt(dt) = exp(lt)/sqrt(100)

  const float2* __restrict__ noise2 = (const float2*)noise;
  const float* hbase = &hrec[jbase * 8];

  for (int step = 0; step < STEPS; ++step) {
    // issue the noise load early; latency hides under the j-loop
    const float2 nz = noise2[(size_t)step*N_PTS + p];

    float Jm[3][2] = {}, Js[3][2] = {}, Km[3][3] = {}, Ks[3][3] = {};
    #pragma unroll
    for (int jj = 0; jj < 25; ++jj) {
      const float4 h0 = *(const float4*)(hbase + jj*8);      // {m0,m1,m2,s0}
      const float2 h1 = *(const float2*)(hbase + jj*8 + 4);  // {s1,s2}
      const float W0 = W0r[jj], W1 = W1r[jj];
      float a   = fmaf(z0, W0, fmaf(z1, W1, brr[jj]));
      float e   = __expf(-a);
      float sig = __builtin_amdgcn_rcpf(1.f + e);
      float t1  = 1.f - sig;
      float pp  = sig * t1;
      float u   = fmaf(a, pp, sig);                          // swish'
      float u2  = pp * fmaf(a, fmaf(-2.f, sig, 1.f), 2.f);   // swish''
      float c0  = u*W0,  c1  = u*W1;
      float r0  = u2*W0, r1  = u2*W1;
      float q00 = r0*W0, q01 = r0*W1, q11 = r1*W1;
      const float mw[3] = {h0.x, h0.y, h0.z};
      const float sw[3] = {h0.w, h1.x, h1.y};
      #pragma unroll
      for (int o = 0; o < 3; ++o) {
        Jm[o][0] = fmaf(mw[o], c0,  Jm[o][0]);
        Jm[o][1] = fmaf(mw[o], c1,  Jm[o][1]);
        Js[o][0] = fmaf(sw[o], c0,  Js[o][0]);
        Js[o][1] = fmaf(sw[o], c1,  Js[o][1]);
        Km[o][0] = fmaf(mw[o], q00, Km[o][0]);
        Km[o][1] = fmaf(mw[o], q01, Km[o][1]);
        Km[o][2] = fmaf(mw[o], q11, Km[o][2]);
        Ks[o][0] = fmaf(sw[o], q00, Ks[o][0]);
        Ks[o][1] = fmaf(sw[o], q01, Ks[o][1]);
        Ks[o][2] = fmaf(sw[o], q11, Ks[o][2]);
      }
    }
    // complete the j-sums across the quad (linear, so reduce before products)
    #pragma unroll
    for (int o = 0; o < 3; ++o) {
      Jm[o][0]=qreduce(Jm[o][0]); Jm[o][1]=qreduce(Jm[o][1]);
      Js[o][0]=qreduce(Js[o][0]); Js[o][1]=qreduce(Js[o][1]);
      Km[o][0]=qreduce(Km[o][0]); Km[o][1]=qreduce(Km[o][1]); Km[o][2]=qreduce(Km[o][2]);
      Ks[o][0]=qreduce(Ks[o][0]); Ks[o][1]=qreduce(Ks[o][1]); Ks[o][2]=qreduce(Ks[o][2]);
    }

    // G = J^T J (2x2 sym)
    float G00=0.f, G01=0.f, G11=0.f;
    #pragma unroll
    for (int o = 0; o < 3; ++o) {
      G00 += Jm[o][0]*Jm[o][0] + Js[o][0]*Js[o][0];
      G01 += Jm[o][0]*Jm[o][1] + Js[o][0]*Js[o][1];
      G11 += Jm[o][1]*Jm[o][1] + Js[o][1]*Js[o][1];
    }
    // D[c][l] = dG[km]/dz_l (sym in k,m)
    float D00=0.f, D01=0.f, D10=0.f, D11=0.f, D20=0.f, D21=0.f;
    #pragma unroll
    for (int o = 0; o < 3; ++o) {
      D00 += 2.f*(Km[o][0]*Jm[o][0] + Ks[o][0]*Js[o][0]);
      D01 += 2.f*(Km[o][1]*Jm[o][0] + Ks[o][1]*Js[o][0]);
      D10 += Km[o][0]*Jm[o][1] + Jm[o][0]*Km[o][1] + Ks[o][0]*Js[o][1] + Js[o][0]*Ks[o][1];
      D11 += Km[o][1]*Jm[o][1] + Jm[o][0]*Km[o][2] + Ks[o][1]*Js[o][1] + Js[o][0]*Ks[o][2];
      D20 += 2.f*(Km[o][1]*Jm[o][1] + Ks[o][1]*Js[o][1]);
      D21 += 2.f*(Km[o][2]*Jm[o][1] + Ks[o][2]*Js[o][1]);
    }
    const float det = fmaf(G00, G11, -G01*G01);
    const float id  = __builtin_amdgcn_rcpf(det);
    const float i00 = G11*id, i01 = -G01*id, i11 = G00*id;
    // T[k,l,m] = Dg[k,m,l] + Dg[l,m,k] - Dg[k,l,m]
    const float T000 = D00;
    const float T001 = 2.f*D10 - D01;
    const float T010 = D01;
    const float T011 = D20;
    const float T110 = 2.f*D11 - D20;
    const float T111 = D21;
    // Chris[i][c] = 0.5 * ginv[i,m] T[k,l,m]
    const float C00 = 0.5f*(i00*T000 + i01*T001);
    const float C01 = 0.5f*(i00*T010 + i01*T011);
    const float C02 = 0.5f*(i00*T110 + i01*T111);
    const float C10 = 0.5f*(i01*T000 + i11*T001);
    const float C11 = 0.5f*(i01*T010 + i11*T011);
    const float C12 = 0.5f*(i01*T110 + i11*T111);
    // drift[i] = 0.5 * ginv[j,k] Chris[i,j,k]
    const float dr0 = 0.5f*(i00*C00 + 2.f*i01*C01 + i11*C02);
    const float dr1 = 0.5f*(i00*C10 + 2.f*i01*C11 + i11*C12);

    const float dw0 = sdt*nz.x, dw1 = sdt*nz.y;
    z0 += dr0 + i00*dw0 + i01*dw1;   // + ginv @ dW
    z1 += dr1 + i01*dw0 + i11*dw1;
  }

  // ---- final decode on z ----
  float macc[3] = {}, sacc[3] = {};
  #pragma unroll
  for (int jj = 0; jj < 25; ++jj) {
    const float4 h0 = *(const float4*)(hbase + jj*8);
    const float2 h1 = *(const float2*)(hbase + jj*8 + 4);
    float a   = fmaf(z0, W0r[jj], fmaf(z1, W1r[jj], brr[jj]));
    float sig = __builtin_amdgcn_rcpf(1.f + __expf(-a));
    float h   = a * sig;
    macc[0] = fmaf(h, h0.x, macc[0]);
    macc[1] = fmaf(h, h0.y, macc[1]);
    macc[2] = fmaf(h, h0.z, macc[2]);
    sacc[0] = fmaf(h, h0.w, sacc[0]);
    sacc[1] = fmaf(h, h1.x, sacc[1]);
    sacc[2] = fmaf(h, h1.y, sacc[2]);
  }
  #pragma unroll
  for (int o = 0; o < 3; ++o) { macc[o] = qreduce(macc[o]); sacc[o] = qreduce(sacc[o]); }

  if (l == 0) {
    out[OFF_Z + p*2+0] = z0;
    out[OFF_Z + p*2+1] = z1;
    #pragma unroll
    for (int o = 0; o < 3; ++o) {
      out[OFF_MUXZ + p*3 + o] = macc[o] + bdmu[o];
      out[OFF_LSXZ + p*3 + o] = sacc[o] + bds[o];
    }
  }
}

extern "C" void kernel_launch(void* const* d_in, const int* in_sizes, int n_in,
                              void* d_out, int out_size, void* d_ws, size_t ws_size,
                              hipStream_t stream) {
  (void)in_sizes; (void)n_in; (void)d_ws; (void)ws_size; (void)out_size;
  const float* x    = (const float*)d_in[0];
  const float* We1  = (const float*)d_in[1];
  const float* be1  = (const float*)d_in[2];
  const float* We2  = (const float*)d_in[3];
  const float* be2  = (const float*)d_in[4];
  const float* Wmu  = (const float*)d_in[5];
  const float* bmu  = (const float*)d_in[6];
  const float* Wlt  = (const float*)d_in[7];
  const float* blt  = (const float*)d_in[8];
  const float* Wd1  = (const float*)d_in[9];
  const float* bd1  = (const float*)d_in[10];
  const float* Wdmu = (const float*)d_in[11];
  const float* bdmu = (const float*)d_in[12];
  const float* Wds  = (const float*)d_in[13];
  const float* bds  = (const float*)d_in[14];
  const float* bmz  = (const float*)d_in[15];
  const float* blz  = (const float*)d_in[16];
  const float* noise= (const float*)d_in[17];
  float* out = (float*)d_out;

  enc_kernel<<<512, 128, 0, stream>>>(x, We1, be1, We2, be2, Wmu, bmu, Wlt, blt,
                                      bmz, blz, out);
  sde_kernel<<<512, 256, 0, stream>>>(Wd1, bd1, Wdmu, bdmu, Wds, bds, noise, out);
}

// Round 6
// 8448.662 us; speedup vs baseline: 1.2380x; 1.2380x over previous
//
#include <hip/hip_runtime.h>

#define N_PTS 32768
#define HID   100
#define JPAD  104      // HID padded to 8 lanes x 13 j
#define STEPS 100

// Output layout (concatenated flat, fp32):
#define OFF_Z     0
#define OFF_MUXZ  65536
#define OFF_LSXZ  163840
#define OFF_MUZX  262144
#define OFF_LTZX  327680
#define OFF_MUZ   360448
#define OFF_LTZ   425984

typedef float v2f __attribute__((ext_vector_type(2)));

#if __has_builtin(__builtin_elementwise_fma)
#define FMA2(a, b, c) __builtin_elementwise_fma((a), (b), (c))
#else
#define FMA2(a, b, c) ((a) * (b) + (c))
#endif

__device__ __forceinline__ v2f splat(float x) { v2f r; r.x = x; r.y = x; return r; }

// All-reduce sum across 8 consecutive lanes: DPP quad_perm xor1 (0xB1),
// xor2 (0x4E), then ds_swizzle xor4 (BitMode offset (4<<10)|0x1F = 0x101F).
__device__ __forceinline__ float qreduce8(float v) {
  v += __int_as_float(__builtin_amdgcn_update_dpp(0, __float_as_int(v), 0xB1, 0xF, 0xF, true));
  v += __int_as_float(__builtin_amdgcn_update_dpp(0, __float_as_int(v), 0x4E, 0xF, 0xF, true));
  v += __int_as_float(__builtin_amdgcn_ds_swizzle(__float_as_int(v), 0x101F));
  return v;
}

// ---------------- Encoder: x -> h1 -> h2 -> (mu_zx, log_t_zx) ----------------
__global__ __launch_bounds__(128, 1) void enc_kernel(
    const float* __restrict__ x,
    const float* __restrict__ We1, const float* __restrict__ be1,
    const float* __restrict__ We2, const float* __restrict__ be2,
    const float* __restrict__ Wmu, const float* __restrict__ bmu,
    const float* __restrict__ Wlt, const float* __restrict__ blt,
    const float* __restrict__ b_muz, const float* __restrict__ b_ltz,
    float* __restrict__ out)
{
  const int tid = threadIdx.x;
  const int w   = tid >> 6;           // wave 0/1
  const int pb  = tid & 63;           // point within block
  const int p   = blockIdx.x * 64 + pb;
  const int ob  = __builtin_amdgcn_readfirstlane(w * 50);

  const float x0 = x[p*3+0], x1 = x[p*3+1], x2 = x[p*3+2];

  v2f acc2[25];
  #pragma unroll
  for (int i = 0; i < 25; ++i) { acc2[i].x = 0.f; acc2[i].y = 0.f; }

  for (int k = 0; k < HID; ++k) {
    float a   = fmaf(x0, We1[k], fmaf(x1, We1[HID+k], fmaf(x2, We1[2*HID+k], be1[k])));
    float sig = 1.f / (1.f + __expf(-a));
    float h1  = a * sig;
    const v2f hh = splat(h1);
    const v2f* row2 = (const v2f*)(We2 + k*HID + ob);
    #pragma unroll
    for (int oo = 0; oo < 25; ++oo) acc2[oo] = FMA2(hh, row2[oo], acc2[oo]);
  }

  float m0 = 0.f, m1 = 0.f, lt = 0.f;
  #pragma unroll
  for (int oo = 0; oo < 25; ++oo) {
    #pragma unroll
    for (int h = 0; h < 2; ++h) {
      const int o = ob + 2*oo + h;
      float a   = (h ? acc2[oo].y : acc2[oo].x) + be2[o];
      float sig = 1.f / (1.f + __expf(-a));
      float h2  = a * sig;
      m0 = fmaf(h2, Wmu[o*2+0], m0);
      m1 = fmaf(h2, Wmu[o*2+1], m1);
      lt = fmaf(h2, Wlt[o],     lt);
    }
  }

  __shared__ float red[2][64][3];
  red[w][pb][0] = m0; red[w][pb][1] = m1; red[w][pb][2] = lt;
  __syncthreads();
  if (w == 0) {
    m0 += red[1][pb][0] + bmu[0];
    m1 += red[1][pb][1] + bmu[1];
    lt += red[1][pb][2] + blt[0];
    out[OFF_MUZX + p*2+0] = m0;
    out[OFF_MUZX + p*2+1] = m1;
    out[OFF_LTZX + p]     = lt;
    out[OFF_MUZ  + p*2+0] = b_muz[0];
    out[OFF_MUZ  + p*2+1] = b_muz[1];
    out[OFF_LTZ  + p]     = b_ltz[0];
  }
}

// ------------- SDE: 100 Euler-Maruyama steps on the pullback metric ----------
// Block = 256 threads = 32 points, 8 lanes/point, 13 j/lane (j padded to 104;
// pad records are all-zero and contribute 0 to every sum). Grid = 1024 blocks
// -> 4096 waves = 16 waves/CU (2x round-3's occupancy: the experiment).
// LDS record per j (12 floats = 48 B): {W0,W1,b,W00,W01,W11,m0,s0,m1,s1,m2,s2}
// Lane l's records start at l*13*12 floats: l*156%32 banks = 4l apart -> the
// 8 lanes' b128 reads tile all 32 banks, conflict-free; 4 quads broadcast.
// j-loop FULLY unrolled (13 iters): immediate LDS offsets, no address math.
__global__ __launch_bounds__(256, 4) void sde_kernel(
    const float* __restrict__ Wd1,  const float* __restrict__ bd1,
    const float* __restrict__ Wdmu, const float* __restrict__ bdmu,
    const float* __restrict__ Wds,  const float* __restrict__ bds,
    const float* __restrict__ noise,
    float* __restrict__ out)
{
  __shared__ __align__(16) float wrec[JPAD*12];
  const int tid = threadIdx.x;
  for (int idx = tid; idx < JPAD*12; idx += 256) {
    const int j = idx / 12, f = idx - j*12;
    float v = 0.f;
    if (j < HID) {
      const float w0 = Wd1[j], w1 = Wd1[HID + j];
      switch (f) {
        case 0:  v = w0; break;
        case 1:  v = w1; break;
        case 2:  v = bd1[j]; break;
        case 3:  v = w0*w0; break;
        case 4:  v = w0*w1; break;
        case 5:  v = w1*w1; break;
        case 6:  v = Wdmu[j*3+0]; break;
        case 7:  v = Wds [j*3+0]; break;
        case 8:  v = Wdmu[j*3+1]; break;
        case 9:  v = Wds [j*3+1]; break;
        case 10: v = Wdmu[j*3+2]; break;
        default: v = Wds [j*3+2]; break;
      }
    }
    wrec[idx] = v;
  }
  __syncthreads();

  const int l     = tid & 7;                    // lane within octet
  const int p     = blockIdx.x * 32 + (tid >> 3);
  const int jbase = l * 13;

  float z0 = out[OFF_MUZX + p*2+0];
  float z1 = out[OFF_MUZX + p*2+1];
  const float sdt = __expf(out[OFF_LTZX + p]) * 0.1f;  // sqrt(dt) = exp(lt)/sqrt(100)

  const float2* __restrict__ noise2 = (const float2*)noise;
  const float* hbase = &wrec[jbase * 12];

  for (int step = 0; step < STEPS; ++step) {
    // issue the noise load early; latency hides under the j-loop
    const float2 nz = noise2[(size_t)step*N_PTS + p];

    float Jm[3][2] = {}, Js[3][2] = {}, Km[3][3] = {}, Ks[3][3] = {};
    #pragma unroll
    for (int jj = 0; jj < 13; ++jj) {
      const float4 wa = *(const float4*)(hbase + jj*12);      // {W0, W1, b, W00}
      const float4 wb = *(const float4*)(hbase + jj*12 + 4);  // {W01, W11, m0, s0}
      const float4 wc = *(const float4*)(hbase + jj*12 + 8);  // {m1, s1, m2, s2}
      const float W0 = wa.x, W1 = wa.y;
      float a   = fmaf(z0, W0, fmaf(z1, W1, wa.z));
      float e   = __expf(-a);
      float sig = __builtin_amdgcn_rcpf(1.f + e);
      float t1  = 1.f - sig;
      float pp  = sig * t1;
      float u   = fmaf(a, pp, sig);                          // swish'
      float u2  = pp * fmaf(a, fmaf(-2.f, sig, 1.f), 2.f);   // swish''
      float c0  = u*W0,  c1  = u*W1;
      float q00 = u2*wa.w, q01 = u2*wb.x, q11 = u2*wb.y;
      const float mw[3] = {wb.z, wc.x, wc.z};
      const float sw[3] = {wb.w, wc.y, wc.w};
      #pragma unroll
      for (int o = 0; o < 3; ++o) {
        Jm[o][0] = fmaf(mw[o], c0,  Jm[o][0]);
        Jm[o][1] = fmaf(mw[o], c1,  Jm[o][1]);
        Js[o][0] = fmaf(sw[o], c0,  Js[o][0]);
        Js[o][1] = fmaf(sw[o], c1,  Js[o][1]);
        Km[o][0] = fmaf(mw[o], q00, Km[o][0]);
        Km[o][1] = fmaf(mw[o], q01, Km[o][1]);
        Km[o][2] = fmaf(mw[o], q11, Km[o][2]);
        Ks[o][0] = fmaf(sw[o], q00, Ks[o][0]);
        Ks[o][1] = fmaf(sw[o], q01, Ks[o][1]);
        Ks[o][2] = fmaf(sw[o], q11, Ks[o][2]);
      }
    }
    // complete the j-sums across the octet (linear, so reduce before products)
    #pragma unroll
    for (int o = 0; o < 3; ++o) {
      Jm[o][0]=qreduce8(Jm[o][0]); Jm[o][1]=qreduce8(Jm[o][1]);
      Js[o][0]=qreduce8(Js[o][0]); Js[o][1]=qreduce8(Js[o][1]);
      Km[o][0]=qreduce8(Km[o][0]); Km[o][1]=qreduce8(Km[o][1]); Km[o][2]=qreduce8(Km[o][2]);
      Ks[o][0]=qreduce8(Ks[o][0]); Ks[o][1]=qreduce8(Ks[o][1]); Ks[o][2]=qreduce8(Ks[o][2]);
    }

    // G = J^T J (2x2 sym)
    float G00=0.f, G01=0.f, G11=0.f;
    #pragma unroll
    for (int o = 0; o < 3; ++o) {
      G00 += Jm[o][0]*Jm[o][0] + Js[o][0]*Js[o][0];
      G01 += Jm[o][0]*Jm[o][1] + Js[o][0]*Js[o][1];
      G11 += Jm[o][1]*Jm[o][1] + Js[o][1]*Js[o][1];
    }
    // D[c][l] = dG[km]/dz_l (sym in k,m)
    float D00=0.f, D01=0.f, D10=0.f, D11=0.f, D20=0.f, D21=0.f;
    #pragma unroll
    for (int o = 0; o < 3; ++o) {
      D00 += 2.f*(Km[o][0]*Jm[o][0] + Ks[o][0]*Js[o][0]);
      D01 += 2.f*(Km[o][1]*Jm[o][0] + Ks[o][1]*Js[o][0]);
      D10 += Km[o][0]*Jm[o][1] + Jm[o][0]*Km[o][1] + Ks[o][0]*Js[o][1] + Js[o][0]*Ks[o][1];
      D11 += Km[o][1]*Jm[o][1] + Jm[o][0]*Km[o][2] + Ks[o][1]*Js[o][1] + Js[o][0]*Ks[o][2];
      D20 += 2.f*(Km[o][1]*Jm[o][1] + Ks[o][1]*Js[o][1]);
      D21 += 2.f*(Km[o][2]*Jm[o][1] + Ks[o][2]*Js[o][1]);
    }
    const float det = fmaf(G00, G11, -G01*G01);
    const float id  = __builtin_amdgcn_rcpf(det);
    const float i00 = G11*id, i01 = -G01*id, i11 = G00*id;
    // T[k,l,m] = Dg[k,m,l] + Dg[l,m,k] - Dg[k,l,m]
    const float T000 = D00;
    const float T001 = 2.f*D10 - D01;
    const float T010 = D01;
    const float T011 = D20;
    const float T110 = 2.f*D11 - D20;
    const float T111 = D21;
    // Chris[i][c] = 0.5 * ginv[i,m] T[k,l,m]
    const float C00 = 0.5f*(i00*T000 + i01*T001);
    const float C01 = 0.5f*(i00*T010 + i01*T011);
    const float C02 = 0.5f*(i00*T110 + i01*T111);
    const float C10 = 0.5f*(i01*T000 + i11*T001);
    const float C11 = 0.5f*(i01*T010 + i11*T011);
    const float C12 = 0.5f*(i01*T110 + i11*T111);
    // drift[i] = 0.5 * ginv[j,k] Chris[i,j,k]
    const float dr0 = 0.5f*(i00*C00 + 2.f*i01*C01 + i11*C02);
    const float dr1 = 0.5f*(i00*C10 + 2.f*i01*C11 + i11*C12);

    const float dw0 = sdt*nz.x, dw1 = sdt*nz.y;
    z0 += dr0 + i00*dw0 + i01*dw1;   // + ginv @ dW
    z1 += dr1 + i01*dw0 + i11*dw1;
  }

  // ---- final decode on z ----
  float macc[3] = {}, sacc[3] = {};
  #pragma unroll
  for (int jj = 0; jj < 13; ++jj) {
    const float4 wa = *(const float4*)(hbase + jj*12);
    const float4 wb = *(const float4*)(hbase + jj*12 + 4);
    const float4 wc = *(const float4*)(hbase + jj*12 + 8);
    float a   = fmaf(z0, wa.x, fmaf(z1, wa.y, wa.z));
    float sig = __builtin_amdgcn_rcpf(1.f + __expf(-a));
    float h   = a * sig;
    macc[0] = fmaf(h, wb.z, macc[0]);
    macc[1] = fmaf(h, wc.x, macc[1]);
    macc[2] = fmaf(h, wc.z, macc[2]);
    sacc[0] = fmaf(h, wb.w, sacc[0]);
    sacc[1] = fmaf(h, wc.y, sacc[1]);
    sacc[2] = fmaf(h, wc.w, sacc[2]);
  }
  #pragma unroll
  for (int o = 0; o < 3; ++o) { macc[o] = qreduce8(macc[o]); sacc[o] = qreduce8(sacc[o]); }

  if (l == 0) {
    out[OFF_Z + p*2+0] = z0;
    out[OFF_Z + p*2+1] = z1;
    #pragma unroll
    for (int o = 0; o < 3; ++o) {
      out[OFF_MUXZ + p*3 + o] = macc[o] + bdmu[o];
      out[OFF_LSXZ + p*3 + o] = sacc[o] + bds[o];
    }
  }
}

extern "C" void kernel_launch(void* const* d_in, const int* in_sizes, int n_in,
                              void* d_out, int out_size, void* d_ws, size_t ws_size,
                              hipStream_t stream) {
  (void)in_sizes; (void)n_in; (void)d_ws; (void)ws_size; (void)out_size;
  const float* x    = (const float*)d_in[0];
  const float* We1  = (const float*)d_in[1];
  const float* be1  = (const float*)d_in[2];
  const float* We2  = (const float*)d_in[3];
  const float* be2  = (const float*)d_in[4];
  const float* Wmu  = (const float*)d_in[5];
  const float* bmu  = (const float*)d_in[6];
  const float* Wlt  = (const float*)d_in[7];
  const float* blt  = (const float*)d_in[8];
  const float* Wd1  = (const float*)d_in[9];
  const float* bd1  = (const float*)d_in[10];
  const float* Wdmu = (const float*)d_in[11];
  const float* bdmu = (const float*)d_in[12];
  const float* Wds  = (const float*)d_in[13];
  const float* bds  = (const float*)d_in[14];
  const float* bmz  = (const float*)d_in[15];
  const float* blz  = (const float*)d_in[16];
  const float* noise= (const float*)d_in[17];
  float* out = (float*)d_out;

  enc_kernel<<<512, 128, 0, stream>>>(x, We1, be1, We2, be2, Wmu, bmu, Wlt, blt,
                                      bmz, blz, out);
  sde_kernel<<<1024, 256, 0, stream>>>(Wd1, bd1, Wdmu, bdmu, Wds, bds, noise, out);
}

// Round 7
// 700.655 us; speedup vs baseline: 14.9278x; 12.0582x over previous
//
#include <hip/hip_runtime.h>

#define N_PTS 32768
#define HID   100
#define JPAD  104      // HID padded to 8 lanes x 13 j (pad records all-zero)
#define STEPS 100

// Output layout (concatenated flat, fp32):
#define OFF_Z     0
#define OFF_MUXZ  65536
#define OFF_LSXZ  163840
#define OFF_MUZX  262144
#define OFF_LTZX  327680
#define OFF_MUZ   360448
#define OFF_LTZ   425984

typedef float v2f __attribute__((ext_vector_type(2)));

#if __has_builtin(__builtin_elementwise_fma)
#define FMA2(a, b, c) __builtin_elementwise_fma((a), (b), (c))
#else
#define FMA2(a, b, c) ((a) * (b) + (c))
#endif

__device__ __forceinline__ v2f splat(float x) { v2f r; r.x = x; r.y = x; return r; }

// All-reduce sum across 8 consecutive lanes: DPP quad_perm xor1 (0xB1),
// xor2 (0x4E), then ds_swizzle xor4 (BitMode offset (4<<10)|0x1F = 0x101F).
__device__ __forceinline__ float qreduce8(float v) {
  v += __int_as_float(__builtin_amdgcn_update_dpp(0, __float_as_int(v), 0xB1, 0xF, 0xF, true));
  v += __int_as_float(__builtin_amdgcn_update_dpp(0, __float_as_int(v), 0x4E, 0xF, 0xF, true));
  v += __int_as_float(__builtin_amdgcn_ds_swizzle(__float_as_int(v), 0x101F));
  return v;
}

// ---------------- Encoder: x -> h1 -> h2 -> (mu_zx, log_t_zx) ----------------
__global__ __launch_bounds__(128, 1) void enc_kernel(
    const float* __restrict__ x,
    const float* __restrict__ We1, const float* __restrict__ be1,
    const float* __restrict__ We2, const float* __restrict__ be2,
    const float* __restrict__ Wmu, const float* __restrict__ bmu,
    const float* __restrict__ Wlt, const float* __restrict__ blt,
    const float* __restrict__ b_muz, const float* __restrict__ b_ltz,
    float* __restrict__ out)
{
  const int tid = threadIdx.x;
  const int w   = tid >> 6;           // wave 0/1
  const int pb  = tid & 63;           // point within block
  const int p   = blockIdx.x * 64 + pb;
  const int ob  = __builtin_amdgcn_readfirstlane(w * 50);

  const float x0 = x[p*3+0], x1 = x[p*3+1], x2 = x[p*3+2];

  v2f acc2[25];
  #pragma unroll
  for (int i = 0; i < 25; ++i) { acc2[i].x = 0.f; acc2[i].y = 0.f; }

  for (int k = 0; k < HID; ++k) {
    float a   = fmaf(x0, We1[k], fmaf(x1, We1[HID+k], fmaf(x2, We1[2*HID+k], be1[k])));
    float sig = 1.f / (1.f + __expf(-a));
    float h1  = a * sig;
    const v2f hh = splat(h1);
    const v2f* row2 = (const v2f*)(We2 + k*HID + ob);
    #pragma unroll
    for (int oo = 0; oo < 25; ++oo) acc2[oo] = FMA2(hh, row2[oo], acc2[oo]);
  }

  float m0 = 0.f, m1 = 0.f, lt = 0.f;
  #pragma unroll
  for (int oo = 0; oo < 25; ++oo) {
    #pragma unroll
    for (int h = 0; h < 2; ++h) {
      const int o = ob + 2*oo + h;
      float a   = (h ? acc2[oo].y : acc2[oo].x) + be2[o];
      float sig = 1.f / (1.f + __expf(-a));
      float h2  = a * sig;
      m0 = fmaf(h2, Wmu[o*2+0], m0);
      m1 = fmaf(h2, Wmu[o*2+1], m1);
      lt = fmaf(h2, Wlt[o],     lt);
    }
  }

  __shared__ float red[2][64][3];
  red[w][pb][0] = m0; red[w][pb][1] = m1; red[w][pb][2] = lt;
  __syncthreads();
  if (w == 0) {
    m0 += red[1][pb][0] + bmu[0];
    m1 += red[1][pb][1] + bmu[1];
    lt += red[1][pb][2] + blt[0];
    out[OFF_MUZX + p*2+0] = m0;
    out[OFF_MUZX + p*2+1] = m1;
    out[OFF_LTZX + p]     = lt;
    out[OFF_MUZ  + p*2+0] = b_muz[0];
    out[OFF_MUZ  + p*2+1] = b_muz[1];
    out[OFF_LTZ  + p]     = b_ltz[0];
  }
}

// ------------- SDE: 100 Euler-Maruyama steps on the pullback metric ----------
// EXACT r3 loop shape (partial unroll 5, runtime LDS indexing — the only
// structure this compiler lands without scratch spills), but 8 lanes/point and
// 13 j/lane: grid 1024 blocks -> 4096 waves = 4 waves/SIMD (2x r3 occupancy).
// LDS record per j (12 floats = 48 B): {W0,W1,b,W00,W01,W11,m0,s0,m1,s1,m2,s2}
// Lane l's records start at l*156 floats -> bank 4l apart; the octet's
// ds_read_b128s tile all 32 banks disjointly: conflict-free, 8-way broadcast.
__global__ __launch_bounds__(256, 4) void sde_kernel(
    const float* __restrict__ Wd1,  const float* __restrict__ bd1,
    const float* __restrict__ Wdmu, const float* __restrict__ bdmu,
    const float* __restrict__ Wds,  const float* __restrict__ bds,
    const float* __restrict__ noise,
    float* __restrict__ out)
{
  __shared__ __align__(16) float wrec[JPAD*12];
  const int tid = threadIdx.x;
  for (int idx = tid; idx < JPAD*12; idx += 256) {
    const int j = idx / 12, f = idx - j*12;
    float v = 0.f;
    if (j < HID) {
      const float w0 = Wd1[j], w1 = Wd1[HID + j];
      switch (f) {
        case 0:  v = w0; break;
        case 1:  v = w1; break;
        case 2:  v = bd1[j]; break;
        case 3:  v = w0*w0; break;
        case 4:  v = w0*w1; break;
        case 5:  v = w1*w1; break;
        case 6:  v = Wdmu[j*3+0]; break;
        case 7:  v = Wds [j*3+0]; break;
        case 8:  v = Wdmu[j*3+1]; break;
        case 9:  v = Wds [j*3+1]; break;
        case 10: v = Wdmu[j*3+2]; break;
        default: v = Wds [j*3+2]; break;
      }
    }
    wrec[idx] = v;
  }
  __syncthreads();

  const int l     = tid & 7;                    // lane within octet
  const int p     = blockIdx.x * 32 + (tid >> 3);
  const int jbase = l * 13;

  float z0 = out[OFF_MUZX + p*2+0];
  float z1 = out[OFF_MUZX + p*2+1];
  const float sdt = __expf(out[OFF_LTZX + p]) * 0.1f;  // sqrt(dt) = exp(lt)/sqrt(100)

  const float2* __restrict__ noise2 = (const float2*)noise;

  for (int step = 0; step < STEPS; ++step) {
    // issue the noise load early; latency hides under the j-loop
    const float2 nz = noise2[(size_t)step*N_PTS + p];

    float Jm[3][2] = {}, Js[3][2] = {}, Km[3][3] = {}, Ks[3][3] = {};
    #pragma unroll 5
    for (int jj = 0; jj < 13; ++jj) {
      const float* r = &wrec[(jbase + jj)*12];
      const float4 wa = *(const float4*)(r);      // {W0, W1, b, W00}
      const float4 wb = *(const float4*)(r + 4);  // {W01, W11, m0, s0}
      const float4 wc = *(const float4*)(r + 8);  // {m1, s1, m2, s2}
      const float W0 = wa.x, W1 = wa.y;
      float a   = fmaf(z0, W0, fmaf(z1, W1, wa.z));
      float e   = __expf(-a);
      float sig = __builtin_amdgcn_rcpf(1.f + e);
      float t1  = 1.f - sig;
      float pp  = sig * t1;
      float u   = fmaf(a, pp, sig);                          // swish'
      float u2  = pp * fmaf(a, fmaf(-2.f, sig, 1.f), 2.f);   // swish''
      float c0  = u*W0,  c1  = u*W1;
      float q00 = u2*wa.w, q01 = u2*wb.x, q11 = u2*wb.y;
      const float mw[3] = {wb.z, wc.x, wc.z};
      const float sw[3] = {wb.w, wc.y, wc.w};
      #pragma unroll
      for (int o = 0; o < 3; ++o) {
        Jm[o][0] = fmaf(mw[o], c0,  Jm[o][0]);
        Jm[o][1] = fmaf(mw[o], c1,  Jm[o][1]);
        Js[o][0] = fmaf(sw[o], c0,  Js[o][0]);
        Js[o][1] = fmaf(sw[o], c1,  Js[o][1]);
        Km[o][0] = fmaf(mw[o], q00, Km[o][0]);
        Km[o][1] = fmaf(mw[o], q01, Km[o][1]);
        Km[o][2] = fmaf(mw[o], q11, Km[o][2]);
        Ks[o][0] = fmaf(sw[o], q00, Ks[o][0]);
        Ks[o][1] = fmaf(sw[o], q01, Ks[o][1]);
        Ks[o][2] = fmaf(sw[o], q11, Ks[o][2]);
      }
    }
    // complete the j-sums across the octet (linear, so reduce before products)
    #pragma unroll
    for (int o = 0; o < 3; ++o) {
      Jm[o][0]=qreduce8(Jm[o][0]); Jm[o][1]=qreduce8(Jm[o][1]);
      Js[o][0]=qreduce8(Js[o][0]); Js[o][1]=qreduce8(Js[o][1]);
      Km[o][0]=qreduce8(Km[o][0]); Km[o][1]=qreduce8(Km[o][1]); Km[o][2]=qreduce8(Km[o][2]);
      Ks[o][0]=qreduce8(Ks[o][0]); Ks[o][1]=qreduce8(Ks[o][1]); Ks[o][2]=qreduce8(Ks[o][2]);
    }

    // G = J^T J (2x2 sym)
    float G00=0.f, G01=0.f, G11=0.f;
    #pragma unroll
    for (int o = 0; o < 3; ++o) {
      G00 += Jm[o][0]*Jm[o][0] + Js[o][0]*Js[o][0];
      G01 += Jm[o][0]*Jm[o][1] + Js[o][0]*Js[o][1];
      G11 += Jm[o][1]*Jm[o][1] + Js[o][1]*Js[o][1];
    }
    // D[c][l] = dG[km]/dz_l (sym in k,m)
    float D00=0.f, D01=0.f, D10=0.f, D11=0.f, D20=0.f, D21=0.f;
    #pragma unroll
    for (int o = 0; o < 3; ++o) {
      D00 += 2.f*(Km[o][0]*Jm[o][0] + Ks[o][0]*Js[o][0]);
      D01 += 2.f*(Km[o][1]*Jm[o][0] + Ks[o][1]*Js[o][0]);
      D10 += Km[o][0]*Jm[o][1] + Jm[o][0]*Km[o][1] + Ks[o][0]*Js[o][1] + Js[o][0]*Ks[o][1];
      D11 += Km[o][1]*Jm[o][1] + Jm[o][0]*Km[o][2] + Ks[o][1]*Js[o][1] + Js[o][0]*Ks[o][2];
      D20 += 2.f*(Km[o][1]*Jm[o][1] + Ks[o][1]*Js[o][1]);
      D21 += 2.f*(Km[o][2]*Jm[o][1] + Ks[o][2]*Js[o][1]);
    }
    const float det = fmaf(G00, G11, -G01*G01);
    const float id  = __builtin_amdgcn_rcpf(det);
    const float i00 = G11*id, i01 = -G01*id, i11 = G00*id;
    // T[k,l,m] = Dg[k,m,l] + Dg[l,m,k] - Dg[k,l,m]
    const float T000 = D00;
    const float T001 = 2.f*D10 - D01;
    const float T010 = D01;
    const float T011 = D20;
    const float T110 = 2.f*D11 - D20;
    const float T111 = D21;
    // Chris[i][c] = 0.5 * ginv[i,m] T[k,l,m]
    const float C00 = 0.5f*(i00*T000 + i01*T001);
    const float C01 = 0.5f*(i00*T010 + i01*T011);
    const float C02 = 0.5f*(i00*T110 + i01*T111);
    const float C10 = 0.5f*(i01*T000 + i11*T001);
    const float C11 = 0.5f*(i01*T010 + i11*T011);
    const float C12 = 0.5f*(i01*T110 + i11*T111);
    // drift[i] = 0.5 * ginv[j,k] Chris[i,j,k]
    const float dr0 = 0.5f*(i00*C00 + 2.f*i01*C01 + i11*C02);
    const float dr1 = 0.5f*(i00*C10 + 2.f*i01*C11 + i11*C12);

    const float dw0 = sdt*nz.x, dw1 = sdt*nz.y;
    z0 += dr0 + i00*dw0 + i01*dw1;   // + ginv @ dW
    z1 += dr1 + i01*dw0 + i11*dw1;
  }

  // ---- final decode on z ----
  float macc[3] = {}, sacc[3] = {};
  #pragma unroll 5
  for (int jj = 0; jj < 13; ++jj) {
    const float* r = &wrec[(jbase + jj)*12];
    const float4 wa = *(const float4*)(r);
    const float4 wb = *(const float4*)(r + 4);
    const float4 wc = *(const float4*)(r + 8);
    float a   = fmaf(z0, wa.x, fmaf(z1, wa.y, wa.z));
    float sig = __builtin_amdgcn_rcpf(1.f + __expf(-a));
    float h   = a * sig;
    macc[0] = fmaf(h, wb.z, macc[0]);
    macc[1] = fmaf(h, wc.x, macc[1]);
    macc[2] = fmaf(h, wc.z, macc[2]);
    sacc[0] = fmaf(h, wb.w, sacc[0]);
    sacc[1] = fmaf(h, wc.y, sacc[1]);
    sacc[2] = fmaf(h, wc.w, sacc[2]);
  }
  #pragma unroll
  for (int o = 0; o < 3; ++o) { macc[o] = qreduce8(macc[o]); sacc[o] = qreduce8(sacc[o]); }

  if (l == 0) {
    out[OFF_Z + p*2+0] = z0;
    out[OFF_Z + p*2+1] = z1;
    #pragma unroll
    for (int o = 0; o < 3; ++o) {
      out[OFF_MUXZ + p*3 + o] = macc[o] + bdmu[o];
      out[OFF_LSXZ + p*3 + o] = sacc[o] + bds[o];
    }
  }
}

extern "C" void kernel_launch(void* const* d_in, const int* in_sizes, int n_in,
                              void* d_out, int out_size, void* d_ws, size_t ws_size,
                              hipStream_t stream) {
  (void)in_sizes; (void)n_in; (void)d_ws; (void)ws_size; (void)out_size;
  const float* x    = (const float*)d_in[0];
  const float* We1  = (const float*)d_in[1];
  const float* be1  = (const float*)d_in[2];
  const float* We2  = (const float*)d_in[3];
  const float* be2  = (const float*)d_in[4];
  const float* Wmu  = (const float*)d_in[5];
  const float* bmu  = (const float*)d_in[6];
  const float* Wlt  = (const float*)d_in[7];
  const float* blt  = (const float*)d_in[8];
  const float* Wd1  = (const float*)d_in[9];
  const float* bd1  = (const float*)d_in[10];
  const float* Wdmu = (const float*)d_in[11];
  const float* bdmu = (const float*)d_in[12];
  const float* Wds  = (const float*)d_in[13];
  const float* bds  = (const float*)d_in[14];
  const float* bmz  = (const float*)d_in[15];
  const float* blz  = (const float*)d_in[16];
  const float* noise= (const float*)d_in[17];
  float* out = (float*)d_out;

  enc_kernel<<<512, 128, 0, stream>>>(x, We1, be1, We2, be2, Wmu, bmu, Wlt, blt,
                                      bmz, blz, out);
  sde_kernel<<<1024, 256, 0, stream>>>(Wd1, bd1, Wdmu, bdmu, Wds, bds, noise, out);
}